// Round 17
// baseline (121.830 us; speedup 1.0000x reference)
//
#include <hip/hip_runtime.h>
#include <hip/hip_bf16.h>
#include <math.h>

#define EPS 1e-5f

static constexpr int Bb = 8;
static constexpr int Ss = 8192;
static constexpr int Dd = 1024;      // QD = KD = AD
static constexpr int NW = 128;       // pass blocks per batch (interleaved sweep + 2x waves)
static constexpr int NWv = NW * 4;   // waves per batch (512)
static constexpr int TOK = Ss / NWv; // tokens per wave (16)
static constexpr int NPAIR = TOK / 2;
static constexpr int NCH = 128;      // qk chunk count
static constexpr int RC = Dd / NCH;  // rows per chunk (8)

// ---------- helpers ----------

__device__ __forceinline__ float blk_reduce(float v, bool ismax, volatile float* lds) {
#pragma unroll
  for (int msk = 32; msk; msk >>= 1) {
    float o = __shfl_xor(v, msk);
    v = ismax ? fmaxf(v, o) : (v + o);
  }
  int w = threadIdx.x >> 6;
  __syncthreads();
  if ((threadIdx.x & 63) == 0) lds[w] = v;
  __syncthreads();
  return ismax ? fmaxf(fmaxf(lds[0], lds[1]), fmaxf(lds[2], lds[3]))
               : (lds[0] + lds[1] + lds[2] + lds[3]);
}

__device__ __forceinline__ float wred_sum(float v) {
#pragma unroll
  for (int msk = 32; msk; msk >>= 1) v += __shfl_xor(v, msk);
  return v;
}

__device__ __forceinline__ float quantf(float x, float c) {
  return fminf(fmaxf(rintf(x * c), -128.f), 127.f);
}

__device__ __forceinline__ float ternf(float w, float s) {
  return fminf(fmaxf(rintf(w / s), -1.f), 1.f);
}

__device__ __forceinline__ float4 tern4(float4 w, float s) {
  return make_float4(ternf(w.x, s), ternf(w.y, s), ternf(w.z, s), ternf(w.w, s));
}

__device__ __forceinline__ float4 quant4(float4 v, float c) {
  return make_float4(quantf(v.x, c), quantf(v.y, c), quantf(v.z, c), quantf(v.w, c));
}

__device__ __forceinline__ float absmax4(float4 v) {
  return fmaxf(fmaxf(fabsf(v.x), fabsf(v.y)), fmaxf(fabsf(v.z), fabsf(v.w)));
}

// ---------- K1: weight abs-mean scales (last-arriver finalize; proven R4/R9) ----------

__global__ __launch_bounds__(256) void k_scales(
    const float* __restrict__ w0, const float* __restrict__ w1,
    const float* __restrict__ w2, const float* __restrict__ w3,
    double* __restrict__ part, float* __restrict__ scales, int* __restrict__ cnt)
{
  int seg = blockIdx.x >> 6;
  int blk = blockIdx.x & 63;
  const float* w = seg == 0 ? w0 : seg == 1 ? w1 : seg == 2 ? w2 : w3;
  int n4 = (seg == 3 ? (1024 * 2048) : (1024 * 1024)) >> 2;
  const float4* w4 = (const float4*)w;
  double acc = 0.0;
  for (int i = blk * 256 + threadIdx.x; i < n4; i += 64 * 256) {
    float4 v = w4[i];
    acc += (double)fabsf(v.x) + (double)fabsf(v.y)
         + (double)fabsf(v.z) + (double)fabsf(v.w);
  }
  __shared__ double sred[256];
  sred[threadIdx.x] = acc;
  __syncthreads();
  for (int s = 128; s > 0; s >>= 1) {
    if (threadIdx.x < s) sred[threadIdx.x] += sred[threadIdx.x + s];
    __syncthreads();
  }
  __shared__ int lastold;
  if (threadIdx.x == 0) {
    part[blockIdx.x] = sred[0];
    __threadfence();
    lastold = atomicAdd(cnt, 1);
  }
  __syncthreads();
  if (lastold == 255) {
    __threadfence();
    if (threadIdx.x < 4) {
      int sg = threadIdx.x;
      double s = 0.0;
      for (int i = 0; i < 64; i++) s += part[sg * 64 + i];
      double n = (sg == 3) ? 2097152.0 : 1048576.0;
      scales[sg] = (float)(s / n) + EPS;
    }
  }
}

// ---------- K2: fused query quant + ternary GEMV (proven R4/R9) ----------

__global__ __launch_bounds__(256) void k_qgemv(
    const float* __restrict__ query, const float* __restrict__ W,
    const float* __restrict__ bias, const float* __restrict__ scales,
    float* __restrict__ out)
{
  __shared__ float cs[Dd];
  __shared__ float red[4];
  int b = blockIdx.x >> 8, grp = blockIdx.x & 255;
  int tid = threadIdx.x, wv = tid >> 6, lane = tid & 63;
  float4 v = ((const float4*)(query + (size_t)b * Dd))[tid];
  float am = blk_reduce(absmax4(v), true, red);
  float g = am + EPS;
  float c = 127.0f / g;
  ((float4*)cs)[tid] = quant4(v, c);
  __syncthreads();
  float s = scales[0];
  int o = grp * 4 + wv;
  const float4* wr = (const float4*)(W + (size_t)o * Dd);
  float acc = 0.f;
#pragma unroll
  for (int i = 0; i < 4; i++) {
    int idx = i * 64 + lane;
    float4 w4 = wr[idx];
    float4 a4 = ((const float4*)cs)[idx];
    acc += a4.x * ternf(w4.x, s) + a4.y * ternf(w4.y, s)
         + a4.z * ternf(w4.z, s) + a4.w * ternf(w4.w, s);
  }
  acc = wred_sum(acc);
  if (lane == 0) out[(size_t)b * Dd + o] = s * (g / 127.0f) * acc + bias[o];
}

// ---------- K3a: qk chunk partials (128 blocks, RC=8, no spin; R15) ----------

__global__ __launch_bounds__(256) void k_qk_part(
    const float* __restrict__ q, const float* __restrict__ Wk,
    const float* __restrict__ scales, float* __restrict__ part)
{
  __shared__ float qs2[Bb * RC];   // 64 floats
  int ch = blockIdx.x, a0 = ch * RC;
  int tid = threadIdx.x;
  if (tid < Bb * RC) {
    int b = tid >> 3, a = tid & 7;   // RC = 8
    qs2[tid] = q[(size_t)b * Dd + a0 + a];
  }
  __syncthreads();
  float s = scales[1];
  float4 acc[Bb];
#pragma unroll
  for (int b = 0; b < Bb; b++) acc[b] = make_float4(0.f, 0.f, 0.f, 0.f);
  const float4* Wr = (const float4*)(Wk + (size_t)a0 * Dd);
#pragma unroll
  for (int i = 0; i < RC; i++) {
    float4 t4 = tern4(Wr[(size_t)i * 256 + tid], s);
#pragma unroll
    for (int b = 0; b < Bb; b++) {
      float qb = qs2[b * RC + i];
      acc[b].x += qb * t4.x; acc[b].y += qb * t4.y;
      acc[b].z += qb * t4.z; acc[b].w += qb * t4.w;
    }
  }
#pragma unroll
  for (int b = 0; b < Bb; b++)
    ((float4*)part)[((size_t)ch * Bb + b) * 256 + tid] = acc[b];
}

// ---------- K3b: qk combine (128 blocks, all 256 threads) + q.b_k (R15) ----------

__global__ __launch_bounds__(256) void k_qk_comb(
    const float* __restrict__ part, const float* __restrict__ q,
    const float* __restrict__ bk, const float* __restrict__ scales,
    float* __restrict__ qk, float* __restrict__ qdotbk)
{
  __shared__ float4 lred[16][17];
  int b = blockIdx.x >> 4, g = blockIdx.x & 15;
  int tid = threadIdx.x;
  int c = tid & 15, kg = tid >> 4;
  int d4 = g * 16 + c;
  float s = scales[1];
  float4 a = make_float4(0.f, 0.f, 0.f, 0.f);
#pragma unroll
  for (int j = 0; j < NCH / 16; j++) {
    int ch = kg * (NCH / 16) + j;
    float4 p = ((const float4*)part)[((size_t)ch * Bb + b) * 256 + d4];
    a.x += p.x; a.y += p.y; a.z += p.z; a.w += p.w;
  }
  lred[kg][c] = a;
  __syncthreads();
  if (kg == 0) {
    float4 t = lred[0][c];
#pragma unroll
    for (int k = 1; k < 16; k++) {
      float4 v = lred[k][c];
      t.x += v.x; t.y += v.y; t.z += v.z; t.w += v.w;
    }
    ((float4*)qk)[(size_t)b * 256 + d4] =
        make_float4(s * t.x, s * t.y, s * t.z, s * t.w);
  } else if (g == 0 && tid >= 64 && tid < 128) {
    int lane = tid - 64;
    float p = 0.f;
    for (int a2 = lane; a2 < Dd; a2 += 64) p += q[(size_t)b * Dd + a2] * bk[a2];
    p = wred_sum(p);
    if (lane == 0) qdotbk[b] = p;
  }
}

// ---------- K4: streaming pass; interleaved ownership + NW=128 (4x waves/SIMD) ----------

__global__ __launch_bounds__(256) void k_pass(
    const float* __restrict__ X, const float* __restrict__ qk,
    const float* __restrict__ qdotbk,
    float* __restrict__ m_part, float* __restrict__ l_part,
    float* __restrict__ t_part)
{
  int b    = blockIdx.x >> 7;
  int wg   = blockIdx.x & 127;
  int wv   = threadIdx.x >> 6;
  int lane = threadIdx.x & 63;
  int widx = wg * 4 + wv;

  const float4* qkb = (const float4*)(qk + (size_t)b * Dd);
  float4 qv0 = qkb[lane], qv1 = qkb[64 + lane], qv2 = qkb[128 + lane], qv3 = qkb[192 + lane];
  float qb = qdotbk[b];
  const float4* Xb = (const float4*)(X + (size_t)b * Ss * Dd);

  auto tokoff = [&](int k) -> size_t {
    return (size_t)(widx + k * NWv) * 256;
  };

  float m = -INFINITY, l = 0.f;
  float4 a0 = make_float4(0,0,0,0), a1 = a0, a2 = a0, a3 = a0;

  size_t oA = tokoff(0), oB = tokoff(1);
  float4 xA0 = Xb[oA + lane], xA1 = Xb[oA + 64 + lane], xA2 = Xb[oA + 128 + lane], xA3 = Xb[oA + 192 + lane];
  float4 xB0 = Xb[oB + lane], xB1 = Xb[oB + 64 + lane], xB2 = Xb[oB + 128 + lane], xB3 = Xb[oB + 192 + lane];

  for (int p = 0; p < NPAIR; p++) {
    int kn = (p + 1 < NPAIR) ? 2 * p + 2 : 2 * p;
    size_t nA = tokoff(kn), nB = tokoff(kn + 1);
    float4 nA0 = Xb[nA + lane], nA1 = Xb[nA + 64 + lane],
           nA2 = Xb[nA + 128 + lane], nA3 = Xb[nA + 192 + lane];
    float4 nB0 = Xb[nB + lane], nB1 = Xb[nB + 64 + lane],
           nB2 = Xb[nB + 128 + lane], nB3 = Xb[nB + 192 + lane];

    float amA = fmaxf(fmaxf(absmax4(xA0), absmax4(xA1)), fmaxf(absmax4(xA2), absmax4(xA3)));
    float amB = fmaxf(fmaxf(absmax4(xB0), absmax4(xB1)), fmaxf(absmax4(xB2), absmax4(xB3)));
#pragma unroll
    for (int msk = 32; msk; msk >>= 1) {
      float oAm = __shfl_xor(amA, msk);
      float oBm = __shfl_xor(amB, msk);
      amA = fmaxf(amA, oAm);
      amB = fmaxf(amB, oBm);
    }
    float gA = amA + EPS, gB = amB + EPS;
    float cA = 127.0f / gA, cB = 127.0f / gB;
    float giA = gA / 127.0f, giB = gB / 127.0f;

    float qA00 = quantf(xA0.x, cA), qA01 = quantf(xA0.y, cA), qA02 = quantf(xA0.z, cA), qA03 = quantf(xA0.w, cA);
    float qA10 = quantf(xA1.x, cA), qA11 = quantf(xA1.y, cA), qA12 = quantf(xA1.z, cA), qA13 = quantf(xA1.w, cA);
    float qA20 = quantf(xA2.x, cA), qA21 = quantf(xA2.y, cA), qA22 = quantf(xA2.z, cA), qA23 = quantf(xA2.w, cA);
    float qA30 = quantf(xA3.x, cA), qA31 = quantf(xA3.y, cA), qA32 = quantf(xA3.z, cA), qA33 = quantf(xA3.w, cA);
    float qB00 = quantf(xB0.x, cB), qB01 = quantf(xB0.y, cB), qB02 = quantf(xB0.z, cB), qB03 = quantf(xB0.w, cB);
    float qB10 = quantf(xB1.x, cB), qB11 = quantf(xB1.y, cB), qB12 = quantf(xB1.z, cB), qB13 = quantf(xB1.w, cB);
    float qB20 = quantf(xB2.x, cB), qB21 = quantf(xB2.y, cB), qB22 = quantf(xB2.z, cB), qB23 = quantf(xB2.w, cB);
    float qB30 = quantf(xB3.x, cB), qB31 = quantf(xB3.y, cB), qB32 = quantf(xB3.z, cB), qB33 = quantf(xB3.w, cB);

    float dtA = qA00 * qv0.x + qA01 * qv0.y + qA02 * qv0.z + qA03 * qv0.w
              + qA10 * qv1.x + qA11 * qv1.y + qA12 * qv1.z + qA13 * qv1.w
              + qA20 * qv2.x + qA21 * qv2.y + qA22 * qv2.z + qA23 * qv2.w
              + qA30 * qv3.x + qA31 * qv3.y + qA32 * qv3.z + qA33 * qv3.w;
    float dtB = qB00 * qv0.x + qB01 * qv0.y + qB02 * qv0.z + qB03 * qv0.w
              + qB10 * qv1.x + qB11 * qv1.y + qB12 * qv1.z + qB13 * qv1.w
              + qB20 * qv2.x + qB21 * qv2.y + qB22 * qv2.z + qB23 * qv2.w
              + qB30 * qv3.x + qB31 * qv3.y + qB32 * qv3.z + qB33 * qv3.w;
#pragma unroll
    for (int msk = 32; msk; msk >>= 1) {
      float oAd = __shfl_xor(dtA, msk);
      float oBd = __shfl_xor(dtB, msk);
      dtA += oAd;
      dtB += oBd;
    }

    float sA = (dtA * giA + qb) * 0.03125f;   // / sqrt(1024)
    float sB = (dtB * giB + qb) * 0.03125f;

    float mn  = fmaxf(m, fmaxf(sA, sB));
    float scl = __expf(m - mn);               // first iter: exp(-inf)=0
    float eA  = __expf(sA - mn);
    float eB  = __expf(sB - mn);
    l = l * scl + eA + eB;
    float cfA = eA * giA, cfB = eB * giB;
    a0.x = a0.x * scl + cfA * qA00 + cfB * qB00; a0.y = a0.y * scl + cfA * qA01 + cfB * qB01;
    a0.z = a0.z * scl + cfA * qA02 + cfB * qB02; a0.w = a0.w * scl + cfA * qA03 + cfB * qB03;
    a1.x = a1.x * scl + cfA * qA10 + cfB * qB10; a1.y = a1.y * scl + cfA * qA11 + cfB * qB11;
    a1.z = a1.z * scl + cfA * qA12 + cfB * qB12; a1.w = a1.w * scl + cfA * qA13 + cfB * qB13;
    a2.x = a2.x * scl + cfA * qA20 + cfB * qB20; a2.y = a2.y * scl + cfA * qA21 + cfB * qB21;
    a2.z = a2.z * scl + cfA * qA22 + cfB * qB22; a2.w = a2.w * scl + cfA * qA23 + cfB * qB23;
    a3.x = a3.x * scl + cfA * qA30 + cfB * qB30; a3.y = a3.y * scl + cfA * qA31 + cfB * qB31;
    a3.z = a3.z * scl + cfA * qA32 + cfB * qB32; a3.w = a3.w * scl + cfA * qA33 + cfB * qB33;
    m = mn;

    xA0 = nA0; xA1 = nA1; xA2 = nA2; xA3 = nA3;
    xB0 = nB0; xB1 = nB1; xB2 = nB2; xB3 = nB3;
  }

  size_t pidx = (size_t)b * NWv + widx;
  float4* tpw = (float4*)t_part + (size_t)pidx * 256;
  tpw[lane] = a0; tpw[64 + lane] = a1; tpw[128 + lane] = a2; tpw[192 + lane] = a3;
  if (lane == 0) { m_part[pidx] = m; l_part[pidx] = l; }
}

// ---------- K5: fused combine for 512 partials (R8-proven variant) ----------

__global__ __launch_bounds__(256) void k_comb(
    const float* __restrict__ m_part, const float* __restrict__ l_part,
    const float* __restrict__ t_part, float* __restrict__ t16,
    float* __restrict__ t, int* __restrict__ cnt)
{
  __shared__ float red[4];
  int b = blockIdx.x >> 4, k = blockIdx.x & 15;
  int tid = threadIdx.x;
  float m1 = m_part[(size_t)b * NWv + tid];
  float m2 = m_part[(size_t)b * NWv + 256 + tid];
  float M = blk_reduce(fmaxf(m1, m2), true, red);
  float li = l_part[(size_t)b * NWv + tid] * __expf(m1 - M)
           + l_part[(size_t)b * NWv + 256 + tid] * __expf(m2 - M);
  float L = blk_reduce(li, false, red);

  float4 acc = make_float4(0,0,0,0);
  for (int i = 0; i < 32; i++) {
    size_t pi = (size_t)b * NWv + k * 32 + i;
    float w = __expf(m_part[pi] - M);
    float4 tp = ((const float4*)t_part)[pi * 256 + tid];
    acc.x += w * tp.x; acc.y += w * tp.y; acc.z += w * tp.z; acc.w += w * tp.w;
  }
  ((float4*)t16)[((size_t)(b * 16 + k)) * 256 + tid] = acc;

  __shared__ int lastold;
  if (tid == 0) {
    __threadfence();
    lastold = atomicAdd(&cnt[b], 1);
  }
  __syncthreads();
  if (lastold == 15) {
    __threadfence();
    float invL = 1.0f / L;
    float4 a = make_float4(0,0,0,0);
    for (int kk = 0; kk < 16; kk++) {
      float4 v = ((const float4*)t16)[((size_t)(b * 16 + kk)) * 256 + tid];
      a.x += v.x; a.y += v.y; a.z += v.z; a.w += v.w;
    }
    ((float4*)t)[(size_t)b * 256 + tid] =
        make_float4(a.x * invL, a.y * invL, a.z * invL, a.w * invL);
  }
}

// ---------- K6: ternary GEMV, fp32 activations (proven R4/R9) ----------

__global__ __launch_bounds__(256) void k_tern_gemv_f32(
    const float* __restrict__ act, const float* __restrict__ W,
    const float* __restrict__ bias, const float* __restrict__ scales, int sidx,
    float* __restrict__ out, int K, int N)
{
  int wave = blockIdx.x * 4 + (threadIdx.x >> 6);
  int lane = threadIdx.x & 63;
  int b = wave / N, o = wave - b * N;
  float s = scales[sidx];
  const float4* wr = (const float4*)(W + (size_t)o * K);
  const float4* ar = (const float4*)(act + (size_t)b * K);
  int n4 = K >> 2;
  float acc = 0.f;
  for (int i = lane; i < n4; i += 64) {
    float4 w4 = wr[i];
    float4 a4 = ar[i];
    acc += a4.x * ternf(w4.x, s) + a4.y * ternf(w4.y, s)
         + a4.z * ternf(w4.z, s) + a4.w * ternf(w4.w, s);
  }
  acc = wred_sum(acc);
  if (lane == 0) out[(size_t)b * N + o] = s * acc + bias[o];
}

// ---------- K7: fused [query,ctx] quant + final ternary GEMV (proven R4/R9) ----------

__global__ __launch_bounds__(256) void k_final(
    const float* __restrict__ query, const float* __restrict__ ctx,
    const float* __restrict__ W, const float* __restrict__ bias,
    const float* __restrict__ scales, float* __restrict__ out)
{
  __shared__ float cs[2 * Dd];
  __shared__ float red[4];
  int b = blockIdx.x >> 8, grp = blockIdx.x & 255;
  int tid = threadIdx.x, wv = tid >> 6, lane = tid & 63;
  float4 vq = ((const float4*)(query + (size_t)b * Dd))[tid];
  float4 vc = ((const float4*)(ctx   + (size_t)b * Dd))[tid];
  float am = blk_reduce(fmaxf(absmax4(vq), absmax4(vc)), true, red);
  float g = am + EPS;
  float c = 127.0f / g;
  ((float4*)cs)[tid]       = quant4(vq, c);
  ((float4*)cs)[256 + tid] = quant4(vc, c);
  __syncthreads();
  float s = scales[3];
  int o = grp * 4 + wv;
  const float4* wr = (const float4*)(W + (size_t)o * 2 * Dd);
  float acc = 0.f;
#pragma unroll
  for (int i = 0; i < 8; i++) {
    int idx = i * 64 + lane;
    float4 w4 = wr[idx];
    float4 a4 = ((const float4*)cs)[idx];
    acc += a4.x * ternf(w4.x, s) + a4.y * ternf(w4.y, s)
         + a4.z * ternf(w4.z, s) + a4.w * ternf(w4.w, s);
  }
  acc = wred_sum(acc);
  if (lane == 0) out[(size_t)b * Dd + o] = s * (g / 127.0f) * acc + bias[o];
}

// ---------- launch ----------

extern "C" void kernel_launch(void* const* d_in, const int* in_sizes, int n_in,
                              void* d_out, int out_size, void* d_ws, size_t ws_size,
                              hipStream_t stream)
{
  const float* query = (const float*)d_in[0];
  const float* X     = (const float*)d_in[1];
  const float* w_q   = (const float*)d_in[2];
  const float* b_q   = (const float*)d_in[3];
  const float* w_k   = (const float*)d_in[4];
  const float* b_k   = (const float*)d_in[5];
  const float* w_v   = (const float*)d_in[6];
  const float* b_v   = (const float*)d_in[7];
  const float* w_c   = (const float*)d_in[8];
  const float* b_c   = (const float*)d_in[9];
  float* out = (float*)d_out;
  char* ws = (char*)d_ws;

  size_t off = 0;
  auto alloc = [&](size_t bytes) -> size_t {
    size_t o = off;
    off += (bytes + 255) & ~(size_t)255;
    return o;
  };
  size_t o_cnt    = alloc(256);                 // [0]=scales, [2..9]=comb
  size_t o_part   = alloc(256 * sizeof(double));
  size_t o_scales = alloc(4 * sizeof(float));
  size_t o_q      = alloc((size_t)Bb * Dd * 4);
  size_t o_qk     = alloc((size_t)Bb * Dd * 4);
  size_t o_qbk    = alloc(Bb * sizeof(float));
  size_t o_t      = alloc((size_t)Bb * Dd * 4);
  size_t o_ctx    = alloc((size_t)Bb * Dd * 4);
  size_t o_t16    = alloc((size_t)Bb * 16 * Dd * 4);
  size_t o_qkp    = alloc((size_t)NCH * Bb * Dd * 4);
  size_t o_mp     = alloc((size_t)Bb * NWv * 4);
  size_t o_lp     = alloc((size_t)Bb * NWv * 4);
  size_t o_tp     = alloc((size_t)Bb * NWv * Dd * 4);
  (void)ws_size;

  int*    cnt    = (int*)(ws + o_cnt);
  double* part   = (double*)(ws + o_part);
  float*  scales = (float*)(ws + o_scales);
  float*  qv     = (float*)(ws + o_q);
  float*  qk     = (float*)(ws + o_qk);
  float*  qbk    = (float*)(ws + o_qbk);
  float*  tvec   = (float*)(ws + o_t);
  float*  ctx    = (float*)(ws + o_ctx);
  float*  t16    = (float*)(ws + o_t16);
  float*  qkp    = (float*)(ws + o_qkp);
  float*  mp     = (float*)(ws + o_mp);
  float*  lp     = (float*)(ws + o_lp);
  float*  tp     = (float*)(ws + o_tp);

  hipMemsetAsync(ws + o_cnt, 0, 256, stream);
  k_scales<<<256, 256, 0, stream>>>(w_q, w_k, w_v, w_c, part, scales, &cnt[0]);
  k_qgemv<<<Bb * 256, 256, 0, stream>>>(query, w_q, b_q, scales, qv);
  k_qk_part<<<NCH, 256, 0, stream>>>(qv, w_k, scales, qkp);
  k_qk_comb<<<Bb * 16, 256, 0, stream>>>(qkp, qv, b_k, scales, qk, qbk);
  k_pass<<<Bb * NW, 256, 0, stream>>>(X, qk, qbk, mp, lp, tp);
  k_comb<<<Bb * 16, 256, 0, stream>>>(mp, lp, tp, t16, tvec, &cnt[2]);
  k_tern_gemv_f32<<<(Bb * Dd) / 4, 256, 0, stream>>>(tvec, w_v, b_v, scales, 2, ctx, Dd, Dd);
  k_final<<<Bb * 256, 256, 0, stream>>>(query, ctx, w_c, b_c, scales, out);
}

// Round 18
// 118.326 us; speedup vs baseline: 1.0296x; 1.0296x over previous
//
#include <hip/hip_runtime.h>
#include <hip/hip_bf16.h>
#include <math.h>

#define EPS 1e-5f

static constexpr int Bb = 8;
static constexpr int Ss = 8192;
static constexpr int Dd = 1024;      // QD = KD = AD
static constexpr int NW = 64;        // pass blocks per batch (R16 best)
static constexpr int NWv = NW * 4;   // waves per batch (256)
static constexpr int TOK = Ss / NWv; // tokens per wave (32)
static constexpr int NPAIR = TOK / 2;
static constexpr int NCH = 128;      // qk chunk count
static constexpr int RC = Dd / NCH;  // rows per chunk (8)

// ---------- helpers ----------

__device__ __forceinline__ float blk_reduce(float v, bool ismax, volatile float* lds) {
#pragma unroll
  for (int msk = 32; msk; msk >>= 1) {
    float o = __shfl_xor(v, msk);
    v = ismax ? fmaxf(v, o) : (v + o);
  }
  int w = threadIdx.x >> 6;
  __syncthreads();
  if ((threadIdx.x & 63) == 0) lds[w] = v;
  __syncthreads();
  return ismax ? fmaxf(fmaxf(lds[0], lds[1]), fmaxf(lds[2], lds[3]))
               : (lds[0] + lds[1] + lds[2] + lds[3]);
}

__device__ __forceinline__ float wred_sum(float v) {
#pragma unroll
  for (int msk = 32; msk; msk >>= 1) v += __shfl_xor(v, msk);
  return v;
}

__device__ __forceinline__ float quantf(float x, float c) {
  return fminf(fmaxf(rintf(x * c), -128.f), 127.f);
}

__device__ __forceinline__ float ternf(float w, float s) {
  return fminf(fmaxf(rintf(w / s), -1.f), 1.f);
}

__device__ __forceinline__ float4 tern4(float4 w, float s) {
  return make_float4(ternf(w.x, s), ternf(w.y, s), ternf(w.z, s), ternf(w.w, s));
}

__device__ __forceinline__ float4 quant4(float4 v, float c) {
  return make_float4(quantf(v.x, c), quantf(v.y, c), quantf(v.z, c), quantf(v.w, c));
}

__device__ __forceinline__ float absmax4(float4 v) {
  return fmaxf(fmaxf(fabsf(v.x), fabsf(v.y)), fmaxf(fabsf(v.z), fabsf(v.w)));
}

// ---------- K1: weight abs-mean scales (last-arriver finalize; proven R4/R9) ----------

__global__ __launch_bounds__(256) void k_scales(
    const float* __restrict__ w0, const float* __restrict__ w1,
    const float* __restrict__ w2, const float* __restrict__ w3,
    double* __restrict__ part, float* __restrict__ scales, int* __restrict__ cnt)
{
  int seg = blockIdx.x >> 6;
  int blk = blockIdx.x & 63;
  const float* w = seg == 0 ? w0 : seg == 1 ? w1 : seg == 2 ? w2 : w3;
  int n4 = (seg == 3 ? (1024 * 2048) : (1024 * 1024)) >> 2;
  const float4* w4 = (const float4*)w;
  double acc = 0.0;
  for (int i = blk * 256 + threadIdx.x; i < n4; i += 64 * 256) {
    float4 v = w4[i];
    acc += (double)fabsf(v.x) + (double)fabsf(v.y)
         + (double)fabsf(v.z) + (double)fabsf(v.w);
  }
  __shared__ double sred[256];
  sred[threadIdx.x] = acc;
  __syncthreads();
  for (int s = 128; s > 0; s >>= 1) {
    if (threadIdx.x < s) sred[threadIdx.x] += sred[threadIdx.x + s];
    __syncthreads();
  }
  __shared__ int lastold;
  if (threadIdx.x == 0) {
    part[blockIdx.x] = sred[0];
    __threadfence();
    lastold = atomicAdd(cnt, 1);
  }
  __syncthreads();
  if (lastold == 255) {
    __threadfence();
    if (threadIdx.x < 4) {
      int sg = threadIdx.x;
      double s = 0.0;
      for (int i = 0; i < 64; i++) s += part[sg * 64 + i];
      double n = (sg == 3) ? 2097152.0 : 1048576.0;
      scales[sg] = (float)(s / n) + EPS;
    }
  }
}

// ---------- K2: fused query quant + ternary GEMV (proven R4/R9) ----------

__global__ __launch_bounds__(256) void k_qgemv(
    const float* __restrict__ query, const float* __restrict__ W,
    const float* __restrict__ bias, const float* __restrict__ scales,
    float* __restrict__ out)
{
  __shared__ float cs[Dd];
  __shared__ float red[4];
  int b = blockIdx.x >> 8, grp = blockIdx.x & 255;
  int tid = threadIdx.x, wv = tid >> 6, lane = tid & 63;
  float4 v = ((const float4*)(query + (size_t)b * Dd))[tid];
  float am = blk_reduce(absmax4(v), true, red);
  float g = am + EPS;
  float c = 127.0f / g;
  ((float4*)cs)[tid] = quant4(v, c);
  __syncthreads();
  float s = scales[0];
  int o = grp * 4 + wv;
  const float4* wr = (const float4*)(W + (size_t)o * Dd);
  float acc = 0.f;
#pragma unroll
  for (int i = 0; i < 4; i++) {
    int idx = i * 64 + lane;
    float4 w4 = wr[idx];
    float4 a4 = ((const float4*)cs)[idx];
    acc += a4.x * ternf(w4.x, s) + a4.y * ternf(w4.y, s)
         + a4.z * ternf(w4.z, s) + a4.w * ternf(w4.w, s);
  }
  acc = wred_sum(acc);
  if (lane == 0) out[(size_t)b * Dd + o] = s * (g / 127.0f) * acc + bias[o];
}

// ---------- K3a: qk chunk partials (128 blocks, RC=8, no spin; R15) ----------

__global__ __launch_bounds__(256) void k_qk_part(
    const float* __restrict__ q, const float* __restrict__ Wk,
    const float* __restrict__ scales, float* __restrict__ part)
{
  __shared__ float qs2[Bb * RC];   // 64 floats
  int ch = blockIdx.x, a0 = ch * RC;
  int tid = threadIdx.x;
  if (tid < Bb * RC) {
    int b = tid >> 3, a = tid & 7;   // RC = 8
    qs2[tid] = q[(size_t)b * Dd + a0 + a];
  }
  __syncthreads();
  float s = scales[1];
  float4 acc[Bb];
#pragma unroll
  for (int b = 0; b < Bb; b++) acc[b] = make_float4(0.f, 0.f, 0.f, 0.f);
  const float4* Wr = (const float4*)(Wk + (size_t)a0 * Dd);
#pragma unroll
  for (int i = 0; i < RC; i++) {
    float4 t4 = tern4(Wr[(size_t)i * 256 + tid], s);
#pragma unroll
    for (int b = 0; b < Bb; b++) {
      float qb = qs2[b * RC + i];
      acc[b].x += qb * t4.x; acc[b].y += qb * t4.y;
      acc[b].z += qb * t4.z; acc[b].w += qb * t4.w;
    }
  }
#pragma unroll
  for (int b = 0; b < Bb; b++)
    ((float4*)part)[((size_t)ch * Bb + b) * 256 + tid] = acc[b];
}

// ---------- K3b: qk combine (128 blocks, all 256 threads) + q.b_k (R15) ----------

__global__ __launch_bounds__(256) void k_qk_comb(
    const float* __restrict__ part, const float* __restrict__ q,
    const float* __restrict__ bk, const float* __restrict__ scales,
    float* __restrict__ qk, float* __restrict__ qdotbk)
{
  __shared__ float4 lred[16][17];
  int b = blockIdx.x >> 4, g = blockIdx.x & 15;
  int tid = threadIdx.x;
  int c = tid & 15, kg = tid >> 4;
  int d4 = g * 16 + c;
  float s = scales[1];
  float4 a = make_float4(0.f, 0.f, 0.f, 0.f);
#pragma unroll
  for (int j = 0; j < NCH / 16; j++) {
    int ch = kg * (NCH / 16) + j;
    float4 p = ((const float4*)part)[((size_t)ch * Bb + b) * 256 + d4];
    a.x += p.x; a.y += p.y; a.z += p.z; a.w += p.w;
  }
  lred[kg][c] = a;
  __syncthreads();
  if (kg == 0) {
    float4 t = lred[0][c];
#pragma unroll
    for (int k = 1; k < 16; k++) {
      float4 v = lred[k][c];
      t.x += v.x; t.y += v.y; t.z += v.z; t.w += v.w;
    }
    ((float4*)qk)[(size_t)b * 256 + d4] =
        make_float4(s * t.x, s * t.y, s * t.z, s * t.w);
  } else if (g == 0 && tid >= 64 && tid < 128) {
    int lane = tid - 64;
    float p = 0.f;
    for (int a2 = lane; a2 < Dd; a2 += 64) p += q[(size_t)b * Dd + a2] * bk[a2];
    p = wred_sum(p);
    if (lane == 0) qdotbk[b] = p;
  }
}

// ---------- K4: streaming pass; INTERLEAVED token ownership (R16 best) ----------
// Wave widx owns tokens widx + k*NWv: the 256 waves of a batch collectively
// sweep one contiguous ~1MB window through X (DRAM-friendly).

__global__ __launch_bounds__(256) void k_pass(
    const float* __restrict__ X, const float* __restrict__ qk,
    const float* __restrict__ qdotbk,
    float* __restrict__ m_part, float* __restrict__ l_part,
    float* __restrict__ t_part)
{
  int b    = blockIdx.x >> 6;
  int wg   = blockIdx.x & 63;
  int wv   = threadIdx.x >> 6;
  int lane = threadIdx.x & 63;
  int widx = wg * 4 + wv;

  const float4* qkb = (const float4*)(qk + (size_t)b * Dd);
  float4 qv0 = qkb[lane], qv1 = qkb[64 + lane], qv2 = qkb[128 + lane], qv3 = qkb[192 + lane];
  float qb = qdotbk[b];
  const float4* Xb = (const float4*)(X + (size_t)b * Ss * Dd);

  auto tokoff = [&](int k) -> size_t {
    return (size_t)(widx + k * NWv) * 256;
  };

  float m = -INFINITY, l = 0.f;
  float4 a0 = make_float4(0,0,0,0), a1 = a0, a2 = a0, a3 = a0;

  size_t oA = tokoff(0), oB = tokoff(1);
  float4 xA0 = Xb[oA + lane], xA1 = Xb[oA + 64 + lane], xA2 = Xb[oA + 128 + lane], xA3 = Xb[oA + 192 + lane];
  float4 xB0 = Xb[oB + lane], xB1 = Xb[oB + 64 + lane], xB2 = Xb[oB + 128 + lane], xB3 = Xb[oB + 192 + lane];

  for (int p = 0; p < NPAIR; p++) {
    int kn = (p + 1 < NPAIR) ? 2 * p + 2 : 2 * p;
    size_t nA = tokoff(kn), nB = tokoff(kn + 1);
    float4 nA0 = Xb[nA + lane], nA1 = Xb[nA + 64 + lane],
           nA2 = Xb[nA + 128 + lane], nA3 = Xb[nA + 192 + lane];
    float4 nB0 = Xb[nB + lane], nB1 = Xb[nB + 64 + lane],
           nB2 = Xb[nB + 128 + lane], nB3 = Xb[nB + 192 + lane];

    float amA = fmaxf(fmaxf(absmax4(xA0), absmax4(xA1)), fmaxf(absmax4(xA2), absmax4(xA3)));
    float amB = fmaxf(fmaxf(absmax4(xB0), absmax4(xB1)), fmaxf(absmax4(xB2), absmax4(xB3)));
#pragma unroll
    for (int msk = 32; msk; msk >>= 1) {
      float oAm = __shfl_xor(amA, msk);
      float oBm = __shfl_xor(amB, msk);
      amA = fmaxf(amA, oAm);
      amB = fmaxf(amB, oBm);
    }
    float gA = amA + EPS, gB = amB + EPS;
    float cA = 127.0f / gA, cB = 127.0f / gB;
    float giA = gA / 127.0f, giB = gB / 127.0f;

    float qA00 = quantf(xA0.x, cA), qA01 = quantf(xA0.y, cA), qA02 = quantf(xA0.z, cA), qA03 = quantf(xA0.w, cA);
    float qA10 = quantf(xA1.x, cA), qA11 = quantf(xA1.y, cA), qA12 = quantf(xA1.z, cA), qA13 = quantf(xA1.w, cA);
    float qA20 = quantf(xA2.x, cA), qA21 = quantf(xA2.y, cA), qA22 = quantf(xA2.z, cA), qA23 = quantf(xA2.w, cA);
    float qA30 = quantf(xA3.x, cA), qA31 = quantf(xA3.y, cA), qA32 = quantf(xA3.z, cA), qA33 = quantf(xA3.w, cA);
    float qB00 = quantf(xB0.x, cB), qB01 = quantf(xB0.y, cB), qB02 = quantf(xB0.z, cB), qB03 = quantf(xB0.w, cB);
    float qB10 = quantf(xB1.x, cB), qB11 = quantf(xB1.y, cB), qB12 = quantf(xB1.z, cB), qB13 = quantf(xB1.w, cB);
    float qB20 = quantf(xB2.x, cB), qB21 = quantf(xB2.y, cB), qB22 = quantf(xB2.z, cB), qB23 = quantf(xB2.w, cB);
    float qB30 = quantf(xB3.x, cB), qB31 = quantf(xB3.y, cB), qB32 = quantf(xB3.z, cB), qB33 = quantf(xB3.w, cB);

    float dtA = qA00 * qv0.x + qA01 * qv0.y + qA02 * qv0.z + qA03 * qv0.w
              + qA10 * qv1.x + qA11 * qv1.y + qA12 * qv1.z + qA13 * qv1.w
              + qA20 * qv2.x + qA21 * qv2.y + qA22 * qv2.z + qA23 * qv2.w
              + qA30 * qv3.x + qA31 * qv3.y + qA32 * qv3.z + qA33 * qv3.w;
    float dtB = qB00 * qv0.x + qB01 * qv0.y + qB02 * qv0.z + qB03 * qv0.w
              + qB10 * qv1.x + qB11 * qv1.y + qB12 * qv1.z + qB13 * qv1.w
              + qB20 * qv2.x + qB21 * qv2.y + qB22 * qv2.z + qB23 * qv2.w
              + qB30 * qv3.x + qB31 * qv3.y + qB32 * qv3.z + qB33 * qv3.w;
#pragma unroll
    for (int msk = 32; msk; msk >>= 1) {
      float oAd = __shfl_xor(dtA, msk);
      float oBd = __shfl_xor(dtB, msk);
      dtA += oAd;
      dtB += oBd;
    }

    float sA = (dtA * giA + qb) * 0.03125f;   // / sqrt(1024)
    float sB = (dtB * giB + qb) * 0.03125f;

    float mn  = fmaxf(m, fmaxf(sA, sB));
    float scl = __expf(m - mn);               // first iter: exp(-inf)=0
    float eA  = __expf(sA - mn);
    float eB  = __expf(sB - mn);
    l = l * scl + eA + eB;
    float cfA = eA * giA, cfB = eB * giB;
    a0.x = a0.x * scl + cfA * qA00 + cfB * qB00; a0.y = a0.y * scl + cfA * qA01 + cfB * qB01;
    a0.z = a0.z * scl + cfA * qA02 + cfB * qB02; a0.w = a0.w * scl + cfA * qA03 + cfB * qB03;
    a1.x = a1.x * scl + cfA * qA10 + cfB * qB10; a1.y = a1.y * scl + cfA * qA11 + cfB * qB11;
    a1.z = a1.z * scl + cfA * qA12 + cfB * qB12; a1.w = a1.w * scl + cfA * qA13 + cfB * qB13;
    a2.x = a2.x * scl + cfA * qA20 + cfB * qB20; a2.y = a2.y * scl + cfA * qA21 + cfB * qB21;
    a2.z = a2.z * scl + cfA * qA22 + cfB * qB22; a2.w = a2.w * scl + cfA * qA23 + cfB * qB23;
    a3.x = a3.x * scl + cfA * qA30 + cfB * qB30; a3.y = a3.y * scl + cfA * qA31 + cfB * qB31;
    a3.z = a3.z * scl + cfA * qA32 + cfB * qB32; a3.w = a3.w * scl + cfA * qA33 + cfB * qB33;
    m = mn;

    xA0 = nA0; xA1 = nA1; xA2 = nA2; xA3 = nA3;
    xB0 = nB0; xB1 = nB1; xB2 = nB2; xB3 = nB3;
  }

  size_t pidx = (size_t)b * NWv + widx;
  float4* tpw = (float4*)t_part + (size_t)pidx * 256;
  tpw[lane] = a0; tpw[64 + lane] = a1; tpw[128 + lane] = a2; tpw[192 + lane] = a3;
  if (lane == 0) { m_part[pidx] = m; l_part[pidx] = l; }
}

// ---------- K5: fused combine (redundant M,L; tree; last-arriver per batch; R9) ----------

__global__ __launch_bounds__(256) void k_comb(
    const float* __restrict__ m_part, const float* __restrict__ l_part,
    const float* __restrict__ t_part, float* __restrict__ t16,
    float* __restrict__ t, int* __restrict__ cnt)
{
  __shared__ float red[4];
  int b = blockIdx.x >> 4, k = blockIdx.x & 15;
  int tid = threadIdx.x;
  float mi = m_part[(size_t)b * NWv + tid];
  float M = blk_reduce(mi, true, red);
  float li = l_part[(size_t)b * NWv + tid] * expf(mi - M);
  float L = blk_reduce(li, false, red);

  float4 acc = make_float4(0,0,0,0);
  for (int i = 0; i < 16; i++) {
    size_t pi = (size_t)b * NWv + k * 16 + i;
    float w = expf(m_part[pi] - M);
    float4 tp = ((const float4*)t_part)[pi * 256 + tid];
    acc.x += w * tp.x; acc.y += w * tp.y; acc.z += w * tp.z; acc.w += w * tp.w;
  }
  ((float4*)t16)[((size_t)(b * 16 + k)) * 256 + tid] = acc;

  __shared__ int lastold;
  if (tid == 0) {
    __threadfence();
    lastold = atomicAdd(&cnt[b], 1);
  }
  __syncthreads();
  if (lastold == 15) {
    __threadfence();
    float invL = 1.0f / L;
    float4 a = make_float4(0,0,0,0);
    for (int kk = 0; kk < 16; kk++) {
      float4 v = ((const float4*)t16)[((size_t)(b * 16 + kk)) * 256 + tid];
      a.x += v.x; a.y += v.y; a.z += v.z; a.w += v.w;
    }
    ((float4*)t)[(size_t)b * 256 + tid] =
        make_float4(a.x * invL, a.y * invL, a.z * invL, a.w * invL);
  }
}

// ---------- K6: ternary GEMV, fp32 activations (proven R4/R9) ----------

__global__ __launch_bounds__(256) void k_tern_gemv_f32(
    const float* __restrict__ act, const float* __restrict__ W,
    const float* __restrict__ bias, const float* __restrict__ scales, int sidx,
    float* __restrict__ out, int K, int N)
{
  int wave = blockIdx.x * 4 + (threadIdx.x >> 6);
  int lane = threadIdx.x & 63;
  int b = wave / N, o = wave - b * N;
  float s = scales[sidx];
  const float4* wr = (const float4*)(W + (size_t)o * K);
  const float4* ar = (const float4*)(act + (size_t)b * K);
  int n4 = K >> 2;
  float acc = 0.f;
  for (int i = lane; i < n4; i += 64) {
    float4 w4 = wr[i];
    float4 a4 = ar[i];
    acc += a4.x * ternf(w4.x, s) + a4.y * ternf(w4.y, s)
         + a4.z * ternf(w4.z, s) + a4.w * ternf(w4.w, s);
  }
  acc = wred_sum(acc);
  if (lane == 0) out[(size_t)b * N + o] = s * acc + bias[o];
}

// ---------- K7: fused [query,ctx] quant + final ternary GEMV (proven R4/R9) ----------

__global__ __launch_bounds__(256) void k_final(
    const float* __restrict__ query, const float* __restrict__ ctx,
    const float* __restrict__ W, const float* __restrict__ bias,
    const float* __restrict__ scales, float* __restrict__ out)
{
  __shared__ float cs[2 * Dd];
  __shared__ float red[4];
  int b = blockIdx.x >> 8, grp = blockIdx.x & 255;
  int tid = threadIdx.x, wv = tid >> 6, lane = tid & 63;
  float4 vq = ((const float4*)(query + (size_t)b * Dd))[tid];
  float4 vc = ((const float4*)(ctx   + (size_t)b * Dd))[tid];
  float am = blk_reduce(fmaxf(absmax4(vq), absmax4(vc)), true, red);
  float g = am + EPS;
  float c = 127.0f / g;
  ((float4*)cs)[tid]       = quant4(vq, c);
  ((float4*)cs)[256 + tid] = quant4(vc, c);
  __syncthreads();
  float s = scales[3];
  int o = grp * 4 + wv;
  const float4* wr = (const float4*)(W + (size_t)o * 2 * Dd);
  float acc = 0.f;
#pragma unroll
  for (int i = 0; i < 8; i++) {
    int idx = i * 64 + lane;
    float4 w4 = wr[idx];
    float4 a4 = ((const float4*)cs)[idx];
    acc += a4.x * ternf(w4.x, s) + a4.y * ternf(w4.y, s)
         + a4.z * ternf(w4.z, s) + a4.w * ternf(w4.w, s);
  }
  acc = wred_sum(acc);
  if (lane == 0) out[(size_t)b * Dd + o] = s * (g / 127.0f) * acc + bias[o];
}

// ---------- launch ----------

extern "C" void kernel_launch(void* const* d_in, const int* in_sizes, int n_in,
                              void* d_out, int out_size, void* d_ws, size_t ws_size,
                              hipStream_t stream)
{
  const float* query = (const float*)d_in[0];
  const float* X     = (const float*)d_in[1];
  const float* w_q   = (const float*)d_in[2];
  const float* b_q   = (const float*)d_in[3];
  const float* w_k   = (const float*)d_in[4];
  const float* b_k   = (const float*)d_in[5];
  const float* w_v   = (const float*)d_in[6];
  const float* b_v   = (const float*)d_in[7];
  const float* w_c   = (const float*)d_in[8];
  const float* b_c   = (const float*)d_in[9];
  float* out = (float*)d_out;
  char* ws = (char*)d_ws;

  size_t off = 0;
  auto alloc = [&](size_t bytes) -> size_t {
    size_t o = off;
    off += (bytes + 255) & ~(size_t)255;
    return o;
  };
  size_t o_cnt    = alloc(256);                 // [0]=scales, [2..9]=comb
  size_t o_part   = alloc(256 * sizeof(double));
  size_t o_scales = alloc(4 * sizeof(float));
  size_t o_q      = alloc((size_t)Bb * Dd * 4);
  size_t o_qk     = alloc((size_t)Bb * Dd * 4);
  size_t o_qbk    = alloc(Bb * sizeof(float));
  size_t o_t      = alloc((size_t)Bb * Dd * 4);
  size_t o_ctx    = alloc((size_t)Bb * Dd * 4);
  size_t o_t16    = alloc((size_t)Bb * 16 * Dd * 4);
  size_t o_qkp    = alloc((size_t)NCH * Bb * Dd * 4);
  size_t o_mp     = alloc((size_t)Bb * NWv * 4);
  size_t o_lp     = alloc((size_t)Bb * NWv * 4);
  size_t o_tp     = alloc((size_t)Bb * NWv * Dd * 4);
  (void)ws_size;

  int*    cnt    = (int*)(ws + o_cnt);
  double* part   = (double*)(ws + o_part);
  float*  scales = (float*)(ws + o_scales);
  float*  qv     = (float*)(ws + o_q);
  float*  qk     = (float*)(ws + o_qk);
  float*  qbk    = (float*)(ws + o_qbk);
  float*  tvec   = (float*)(ws + o_t);
  float*  ctx    = (float*)(ws + o_ctx);
  float*  t16    = (float*)(ws + o_t16);
  float*  qkp    = (float*)(ws + o_qkp);
  float*  mp     = (float*)(ws + o_mp);
  float*  lp     = (float*)(ws + o_lp);
  float*  tp     = (float*)(ws + o_tp);

  hipMemsetAsync(ws + o_cnt, 0, 256, stream);
  k_scales<<<256, 256, 0, stream>>>(w_q, w_k, w_v, w_c, part, scales, &cnt[0]);
  k_qgemv<<<Bb * 256, 256, 0, stream>>>(query, w_q, b_q, scales, qv);
  k_qk_part<<<NCH, 256, 0, stream>>>(qv, w_k, scales, qkp);
  k_qk_comb<<<Bb * 16, 256, 0, stream>>>(qkp, qv, b_k, scales, qk, qbk);
  k_pass<<<Bb * NW, 256, 0, stream>>>(X, qk, qbk, mp, lp, tp);
  k_comb<<<Bb * 16, 256, 0, stream>>>(mp, lp, tp, t16, tvec, &cnt[2]);
  k_tern_gemv_f32<<<(Bb * Dd) / 4, 256, 0, stream>>>(tvec, w_v, b_v, scales, 2, ctx, Dd, Dd);
  k_final<<<Bb * 256, 256, 0, stream>>>(query, ctx, w_c, b_c, scales, out);
}